// Round 4
// baseline (482.578 us; speedup 1.0000x reference)
//
#include <hip/hip_runtime.h>
#include <math.h>

#define F 256
#define Hh 128
#define MAXL 3072

typedef short bf16x8 __attribute__((ext_vector_type(8)));
typedef float f32x4 __attribute__((ext_vector_type(4)));
typedef unsigned int uint4v __attribute__((ext_vector_type(4)));

__device__ inline unsigned short f2bf_rne(float f) {
  unsigned u = __float_as_uint(f);
  unsigned r = u + 0x7fff + ((u >> 16) & 1);
  return (unsigned short)(r >> 16);
}
__device__ inline float bf2f(unsigned short h) {
  return __uint_as_float((unsigned)h << 16);
}

// ---------------------------------------------------------------------------
// K0: zero out, prefix-scan lengths, split W1 into bf16 hi/lo transposed
// chunk-major:  whT[chunk][col][k]  (chunk = k/32, k local 0..31), 8 chunks.
// ---------------------------------------------------------------------------
__global__ void init_kernel(const int* __restrict__ lengths, int* __restrict__ offsets,
                            float* __restrict__ out, const float* __restrict__ W1,
                            unsigned short* __restrict__ whT, unsigned short* __restrict__ wlT,
                            int S, int outN) {
  int t = blockIdx.x * blockDim.x + threadIdx.x;
  int stride = gridDim.x * blockDim.x;
  for (int i = t; i < outN; i += stride) out[i] = 0.f;
  for (int i = t; i < F * Hh; i += stride) {
    int k = i >> 7, col = i & 127;
    float v = W1[i];
    unsigned short h = f2bf_rne(v);
    unsigned short l = f2bf_rne(v - bf2f(h));
    int dst = (k >> 5) * (128 * 32) + col * 32 + (k & 31);
    whT[dst] = h;
    wlT[dst] = l;
  }
  if (blockIdx.x == 0) {
    __shared__ int buf[256];
    int tid = threadIdx.x;
    int v = (tid < S) ? lengths[tid] : 0;
    buf[tid] = v;
    __syncthreads();
    for (int o = 1; o < 256; o <<= 1) {
      int add = (tid >= o) ? buf[tid - o] : 0;
      __syncthreads();
      buf[tid] += add;
      __syncthreads();
    }
    if (tid < S) offsets[tid] = buf[tid] - v;   // exclusive
    if (tid == S - 1) offsets[S] = buf[tid];    // total N
  }
}

// ---------------------------------------------------------------------------
// K1: fused MLP via MFMA.  THIS ROUND: occupancy by structure, not by pin.
//   - Wave tile 32x64 (was 64x64): block = 64 rows x 128 cols, 4 waves 2x2.
//     acc: 32 VGPR (was 64).
//   - Cross-kc x double-buffer: loads for chunk kc+1 issued BEFORE the MFMA
//     section of chunk kc (round-0 drained all loads at each kc boundary ->
//     ~900cy cold-HBM stall per kc per wave at 2-3 waves/SIMD).
//   - No __launch_bounds__ pin (round-1's pin likely spilled).  Natural
//     budget ~125-135 VGPR -> 3-4 waves/SIMD; fail-soft if compiler lands
//     higher.
// Numerics identical: truncation split hi/lo, 3 MFMA passes (hh+hl+lh).
// ---------------------------------------------------------------------------
#define LOADX(B, KC) do {                                             \
    _Pragma("unroll")                                                 \
    for (int rt = 0; rt < 2; ++rt) {                                  \
      a0[B][rt] = make_float4(0.f, 0.f, 0.f, 0.f);                    \
      a1[B][rt] = make_float4(0.f, 0.f, 0.f, 0.f);                    \
      if (rv[rt]) {                                                   \
        a0[B][rt] = *(const float4*)(xb[rt] + (KC) * 32);             \
        a1[B][rt] = *(const float4*)(xb[rt] + (KC) * 32 + 4);         \
      }                                                               \
    }                                                                 \
  } while (0)

__global__ __launch_bounds__(256) void mlp_kernel(
    const float* __restrict__ x,
    const unsigned short* __restrict__ whT, const unsigned short* __restrict__ wlT,
    const float* __restrict__ b1, const float* __restrict__ W2,
    const float* __restrict__ b2, float* __restrict__ yv,
    float* __restrict__ zv, int N) {
  __shared__ float redy[64][2];
  __shared__ float redz[64][2];

  const int t = threadIdx.x;
  const int lane = t & 63;
  const int w = t >> 6;
  const int wr = w >> 1, wc = w & 1;           // wave grid 2x2
  const int ln15 = lane & 15, lq = lane >> 4;  // quad

  const int row0 = blockIdx.x * 64;

  f32x4 acc[2][4];  // [rt][ct]
#pragma unroll
  for (int i = 0; i < 2; ++i)
#pragma unroll
    for (int j = 0; j < 4; ++j) acc[i][j] = (f32x4){0.f, 0.f, 0.f, 0.f};

  bool rv[2];
  const float* xb[2];
#pragma unroll
  for (int rt = 0; rt < 2; ++rt) {
    int rowg = row0 + wr * 32 + rt * 16 + ln15;
    rv[rt] = rowg < N;
    xb[rt] = x + (size_t)rowg * F + lq * 8;    // +kc*32 folds to imm offset
  }
  const int cbase = wc * 64 + ln15;            // + ct*16
  const unsigned short* wb = whT + cbase * 32 + lq * 8;
  const unsigned short* lb = wlT + cbase * 32 + lq * 8;

  float4 a0[2][2], a1[2][2];                   // [buf][rt]
  LOADX(0, 0);                                 // prologue: kc=0 into buf0

#pragma unroll
  for (int kc = 0; kc < 8; ++kc) {
    const int cur = kc & 1, nxt = cur ^ 1;
    if (kc < 7) LOADX(nxt, kc + 1);            // prefetch next chunk early
    bf16x8 bh[4], bl[4];
#pragma unroll
    for (int ct = 0; ct < 4; ++ct) {
      bh[ct] = *(const bf16x8*)(wb + kc * 4096 + ct * 512);
      bl[ct] = *(const bf16x8*)(lb + kc * 4096 + ct * 512);
    }
    // ---- cheap truncation split + MFMA on current buffer ----
#pragma unroll
    for (int rt = 0; rt < 2; ++rt) {
      float f[8] = {a0[cur][rt].x, a0[cur][rt].y, a0[cur][rt].z, a0[cur][rt].w,
                    a1[cur][rt].x, a1[cur][rt].y, a1[cur][rt].z, a1[cur][rt].w};
      union { uint4v u; bf16x8 b; } ah, al;
#pragma unroll
      for (int q = 0; q < 4; ++q) {
        unsigned ua = __float_as_uint(f[2 * q]);
        unsigned ub = __float_as_uint(f[2 * q + 1]);
        // hi = upper-16 truncation, packed pairwise
        ah.u[q] = __builtin_amdgcn_perm(ub, ua, 0x07060302u);
        // exact residual, then truncate-pack
        float ra = f[2 * q]     - __uint_as_float(ua & 0xFFFF0000u);
        float rb = f[2 * q + 1] - __uint_as_float(ub & 0xFFFF0000u);
        al.u[q] = __builtin_amdgcn_perm(__float_as_uint(rb), __float_as_uint(ra), 0x07060302u);
      }
#pragma unroll
      for (int ct = 0; ct < 4; ++ct) {
        acc[rt][ct] = __builtin_amdgcn_mfma_f32_16x16x32_bf16(ah.b, bh[ct], acc[rt][ct], 0, 0, 0);
        acc[rt][ct] = __builtin_amdgcn_mfma_f32_16x16x32_bf16(ah.b, bl[ct], acc[rt][ct], 0, 0, 0);
        acc[rt][ct] = __builtin_amdgcn_mfma_f32_16x16x32_bf16(al.b, bh[ct], acc[rt][ct], 0, 0, 0);
      }
    }
  }

  // ---- epilogue: h = tanh(acc + b1), contract with W2 ----
  // acc[rt][ct][rg]: row = wr*32+rt*16+lq*4+rg, col = wc*64+ct*16+ln15
  float yp[2][4], zp[2][4];
#pragma unroll
  for (int i = 0; i < 2; ++i)
#pragma unroll
    for (int j = 0; j < 4; ++j) { yp[i][j] = 0.f; zp[i][j] = 0.f; }
#pragma unroll
  for (int ct = 0; ct < 4; ++ct) {
    int c = cbase + ct * 16;
    float b1c = b1[c], wyc = W2[2 * c], wzc = W2[2 * c + 1];
#pragma unroll
    for (int rt = 0; rt < 2; ++rt)
#pragma unroll
      for (int rg = 0; rg < 4; ++rg) {
        float a = acc[rt][ct][rg] + b1c;
        float e = __expf(2.f * a);
        float h = 1.f - __fdividef(2.f, e + 1.f);   // tanh(a)
        yp[rt][rg] = fmaf(h, wyc, yp[rt][rg]);
        zp[rt][rg] = fmaf(h, wzc, zp[rt][rg]);
      }
  }
#pragma unroll
  for (int rt = 0; rt < 2; ++rt)
#pragma unroll
    for (int rg = 0; rg < 4; ++rg) {
      float vy = yp[rt][rg], vz = zp[rt][rg];
#pragma unroll
      for (int m = 8; m; m >>= 1) {
        vy += __shfl_xor(vy, m);
        vz += __shfl_xor(vz, m);
      }
      if (ln15 == 0) {
        int row = wr * 32 + rt * 16 + lq * 4 + rg;
        redy[row][wc] = vy;
        redz[row][wc] = vz;
      }
    }
  __syncthreads();
  if (t < 64) {
    int g = row0 + t;
    if (g < N) {
      yv[g] = redy[t][0] + redy[t][1] + b2[0];
      zv[g] = redz[t][0] + redz[t][1] + b2[1];
    }
  }
}
#undef LOADX

// ---------------------------------------------------------------------------
// K2 (fused stats+pool).  THIS ROUND: nchunks 32 -> 8.  Round-3's neutral
// result: at 32 chunks, the redundant per-block stats preamble (~24 strided
// iters over L) dwarfed the ~8 iters of pooling.  At 8 chunks the preamble
// amortizes over 4x more pool work (total redundant stats work drops 8x
// vs round-3) while the BW-bound pool bytes are unchanged.
// Keeps round-2's reverse-stream L3 harvest ordering.
// ---------------------------------------------------------------------------
__device__ inline float wave_reduce_sum(float v) {
#pragma unroll
  for (int o = 32; o; o >>= 1) v += __shfl_down(v, o);
  return v;
}
__device__ inline float wave_reduce_max(float v) {
#pragma unroll
  for (int o = 32; o; o >>= 1) v = fmaxf(v, __shfl_down(v, o));
  return v;
}

__global__ __launch_bounds__(256) void pool_kernel(
    const float* __restrict__ x,
    const float* __restrict__ yv, const float* __restrict__ zv,
    const int* __restrict__ offsets, const int* __restrict__ lengths,
    float* __restrict__ attn, float* __restrict__ out,
    int nchunks, int S) {
  __shared__ float ybuf[MAXL];         // 12 KB
  __shared__ float4 sbuf[4][64];       // 4 KB
  __shared__ float redA[4], redB[4], redC[4];

  const int s = S - 1 - blockIdx.y;
  const int c = nchunks - 1 - blockIdx.x;
  const int off = offsets[s], L = lengths[s];
  const int t = threadIdx.x;
  const int lane = t & 63, wid = t >> 6;   // 4 waves

  // ---- phase 1: stage y, running max ----
  float lmax = -1e30f;
  for (int i = t; i < L; i += 256) {
    float yy = yv[off + i];
    ybuf[i] = yy;
    lmax = fmaxf(lmax, yy);
  }
  lmax = wave_reduce_max(lmax);
  if (lane == 0) redA[wid] = lmax;
  __syncthreads();
  const float ymax = fmaxf(fmaxf(redA[0], redA[1]), fmaxf(redA[2], redA[3]));
  const float invL = 1.f / (float)L;
  __syncthreads();   // protect redA before reuse

  // ---- phase 2: weighted sums ----
  float sw = 0.f, smx = 0.f, sz = 0.f;
  for (int i = t; i < L; i += 256) {
    float wgt = __expf(ybuf[i] - ymax);
    float xp = (float)(i + 1) * invL;
    sw += wgt;
    smx = fmaf(xp, wgt, smx);
    sz += zv[off + i];
  }
  sw = wave_reduce_sum(sw);
  smx = wave_reduce_sum(smx);
  sz = wave_reduce_sum(sz);
  if (lane == 0) { redA[wid] = sw; redB[wid] = smx; redC[wid] = sz; }
  __syncthreads();
  const float wsum = (redA[0] + redA[1]) + (redA[2] + redA[3]);
  const float mxs  = (redB[0] + redB[1]) + (redB[2] + redB[3]);
  const float zsum = (redC[0] + redC[1]) + (redC[2] + redC[3]);
  const float mu = mxs / wsum;
  const float tz = zsum * invL;
  const float sd = fmaxf(tz, 0.f) + log1pf(__expf(-fabsf(tz)));  // softplus
  const float invsd = 1.f / sd;
  const float Cg = 0.3989422804014327f;  // 1/sqrt(2*pi)
  __syncthreads();   // protect redA before reuse

  // ---- phase 3: psum over FULL segment (pure function of i, L, mu, sd) ----
  float ps = 0.f;
  for (int i = t; i < L; i += 256) {
    float xp = (float)(i + 1) * invL;
    float u = (xp - mu) * invsd;
    ps += __expf(-0.5f * u * u);
  }
  ps = wave_reduce_sum(ps);
  if (lane == 0) redA[wid] = ps;
  __syncthreads();
  const float psum = ((redA[0] + redA[1]) + (redA[2] + redA[3])) * (Cg * invsd);
  const float scale = (Cg * invsd) / (psum + 0.001f);   // attn_i = exp(-u^2/2)*scale

  // ---- phase 4: write attn for own chunk (coalesced) ----
  const int i0 = (int)((long long)L * c / nchunks);
  const int i1 = (int)((long long)L * (c + 1) / nchunks);
  for (int i = i0 + t; i < i1; i += 256) {
    float xp = (float)(i + 1) * invL;
    float u = (xp - mu) * invsd;
    attn[off + i] = __expf(-0.5f * u * u) * scale;
  }

  // ---- phase 5: pool own chunk of x, descending rows (L3 harvest) ----
  float4 a0 = make_float4(0.f, 0.f, 0.f, 0.f);
  float4 a1 = make_float4(0.f, 0.f, 0.f, 0.f);
  int i = i1 - 1 - wid;
  for (; i - 4 >= i0; i -= 8) {
    float xpa = (float)(i + 1) * invL;
    float ua = (xpa - mu) * invsd;
    float w0 = __expf(-0.5f * ua * ua) * scale;
    float xpb = (float)(i - 3) * invL;
    float ub = (xpb - mu) * invsd;
    float w1 = __expf(-0.5f * ub * ub) * scale;
    float4 v0 = *(const float4*)&x[(size_t)(off + i) * F + lane * 4];
    float4 v1 = *(const float4*)&x[(size_t)(off + i - 4) * F + lane * 4];
    a0.x = fmaf(w0, v0.x, a0.x); a0.y = fmaf(w0, v0.y, a0.y);
    a0.z = fmaf(w0, v0.z, a0.z); a0.w = fmaf(w0, v0.w, a0.w);
    a1.x = fmaf(w1, v1.x, a1.x); a1.y = fmaf(w1, v1.y, a1.y);
    a1.z = fmaf(w1, v1.z, a1.z); a1.w = fmaf(w1, v1.w, a1.w);
  }
  if (i >= i0) {
    float xpa = (float)(i + 1) * invL;
    float ua = (xpa - mu) * invsd;
    float w0 = __expf(-0.5f * ua * ua) * scale;
    float4 v0 = *(const float4*)&x[(size_t)(off + i) * F + lane * 4];
    a0.x = fmaf(w0, v0.x, a0.x); a0.y = fmaf(w0, v0.y, a0.y);
    a0.z = fmaf(w0, v0.z, a0.z); a0.w = fmaf(w0, v0.w, a0.w);
  }
  a0.x += a1.x; a0.y += a1.y; a0.z += a1.z; a0.w += a1.w;
  sbuf[wid][lane] = a0;
  __syncthreads();
  if (wid == 0) {
    float4 r0 = sbuf[0][lane], r1 = sbuf[1][lane];
    float4 r2 = sbuf[2][lane], r3 = sbuf[3][lane];
    float rx = (r0.x + r1.x) + (r2.x + r3.x);
    float ry = (r0.y + r1.y) + (r2.y + r3.y);
    float rz = (r0.z + r1.z) + (r2.z + r3.z);
    float rw = (r0.w + r1.w) + (r2.w + r3.w);
    float* o = &out[s * F + lane * 4];
    atomicAdd(o + 0, rx);
    atomicAdd(o + 1, ry);
    atomicAdd(o + 2, rz);
    atomicAdd(o + 3, rw);
  }
}

// ---------------------------------------------------------------------------
extern "C" void kernel_launch(void* const* d_in, const int* in_sizes, int n_in,
                              void* d_out, int out_size, void* d_ws, size_t ws_size,
                              hipStream_t stream) {
  const float* x      = (const float*)d_in[0];
  const int* lengths  = (const int*)d_in[1];
  const float* W1     = (const float*)d_in[2];
  const float* b1     = (const float*)d_in[3];
  const float* W2     = (const float*)d_in[4];
  const float* b2     = (const float*)d_in[5];
  const int S = in_sizes[1];
  const int N = in_sizes[0] / F;

  float* out  = (float*)d_out;             // S*F
  float* attn = out + (size_t)S * F;       // N

  int*   offsets = (int*)d_ws;                       // 512 ints (2 KB)
  float* yv = (float*)d_ws + 512;                    // N floats
  float* zv = yv + N;                                // N floats
  unsigned short* whT = (unsigned short*)(zv + N);   // 32768 shorts (64 KB)
  unsigned short* wlT = whT + F * Hh;                // 32768 shorts (64 KB)

  init_kernel<<<64, 256, 0, stream>>>(lengths, offsets, out, W1, whT, wlT, S, S * F);
  mlp_kernel<<<(N + 63) / 64, 256, 0, stream>>>(x, whT, wlT, b1, W2, b2, yv, zv, N);
  pool_kernel<<<dim3(8, S), 256, 0, stream>>>(x, yv, zv, offsets, lengths, attn, out, 8, S);
}

// Round 5
// 472.512 us; speedup vs baseline: 1.0213x; 1.0213x over previous
//
#include <hip/hip_runtime.h>
#include <math.h>

#define F 256
#define Hh 128
#define MAXL 3072

typedef short bf16x8 __attribute__((ext_vector_type(8)));
typedef float f32x4 __attribute__((ext_vector_type(4)));
typedef unsigned int uint4v __attribute__((ext_vector_type(4)));

__device__ inline unsigned short f2bf_rne(float f) {
  unsigned u = __float_as_uint(f);
  unsigned r = u + 0x7fff + ((u >> 16) & 1);
  return (unsigned short)(r >> 16);
}
__device__ inline float bf2f(unsigned short h) {
  return __uint_as_float((unsigned)h << 16);
}

// ---------------------------------------------------------------------------
// K0: zero out, prefix-scan lengths, split W1 into bf16 hi/lo transposed
// chunk-major:  whT[chunk][col][k]  (chunk = k/32, k local 0..31), 8 chunks.
// ---------------------------------------------------------------------------
__global__ void init_kernel(const int* __restrict__ lengths, int* __restrict__ offsets,
                            float* __restrict__ out, const float* __restrict__ W1,
                            unsigned short* __restrict__ whT, unsigned short* __restrict__ wlT,
                            int S, int outN) {
  int t = blockIdx.x * blockDim.x + threadIdx.x;
  int stride = gridDim.x * blockDim.x;
  for (int i = t; i < outN; i += stride) out[i] = 0.f;
  for (int i = t; i < F * Hh; i += stride) {
    int k = i >> 7, col = i & 127;
    float v = W1[i];
    unsigned short h = f2bf_rne(v);
    unsigned short l = f2bf_rne(v - bf2f(h));
    int dst = (k >> 5) * (128 * 32) + col * 32 + (k & 31);
    whT[dst] = h;
    wlT[dst] = l;
  }
  if (blockIdx.x == 0) {
    __shared__ int buf[256];
    int tid = threadIdx.x;
    int v = (tid < S) ? lengths[tid] : 0;
    buf[tid] = v;
    __syncthreads();
    for (int o = 1; o < 256; o <<= 1) {
      int add = (tid >= o) ? buf[tid - o] : 0;
      __syncthreads();
      buf[tid] += add;
      __syncthreads();
    }
    if (tid < S) offsets[tid] = buf[tid] - v;   // exclusive
    if (tid == S - 1) offsets[S] = buf[tid];    // total N
  }
}

// ---------------------------------------------------------------------------
// K1: fused MLP via MFMA.  Round-4 measurement: mlp is LATENCY-bound
// (790 GB/s = 10% HBM, MfmaUtil 12%, VALUBusy 25% -> ~60% stall), and the
// round-0 64x64-wave-tile geometry is best for B-amortization (r4's 32x64
// tile cost +28us in doubled B-fragment work).  THIS ROUND: keep round-0
// geometry, ROTATE the software pipeline across the kc boundary:
//   consume P(rt0,rt1) -> issue P(kc+1) -> consume Q(rt2,rt3) -> issue Q(kc+1)
// so every x-load group has ~2 STEPs + B-issue of compute cover (~750cy at
// 3 waves/SIMD) instead of ~100cy.  Register cost identical to round-0
// (P+Q = 32 VGPR, no pin -> no spill cliff).  Numerics bitwise-identical.
// ---------------------------------------------------------------------------
#define LOADP(KC) do {                                                \
    _Pragma("unroll")                                                 \
    for (int rt = 0; rt < 2; ++rt) {                                  \
      pa0[rt] = make_float4(0.f, 0.f, 0.f, 0.f);                      \
      pa1[rt] = make_float4(0.f, 0.f, 0.f, 0.f);                      \
      if (rv[rt]) {                                                   \
        const float* p = xb[rt] + (KC) * 32;                          \
        pa0[rt] = *(const float4*)p;                                  \
        pa1[rt] = *(const float4*)(p + 4);                            \
      }                                                               \
    }                                                                 \
  } while (0)

#define LOADQ(KC) do {                                                \
    _Pragma("unroll")                                                 \
    for (int rt = 0; rt < 2; ++rt) {                                  \
      qa0[rt] = make_float4(0.f, 0.f, 0.f, 0.f);                      \
      qa1[rt] = make_float4(0.f, 0.f, 0.f, 0.f);                      \
      if (rv[rt + 2]) {                                               \
        const float* p = xb[rt + 2] + (KC) * 32;                      \
        qa0[rt] = *(const float4*)p;                                  \
        qa1[rt] = *(const float4*)(p + 4);                            \
      }                                                               \
    }                                                                 \
  } while (0)

// truncation split of 8 f32 -> bf16 hi/lo + 3 MFMA passes for one rt
#define SPLIT_MFMA(V0, V1, RT) do {                                   \
    float f[8] = {V0.x, V0.y, V0.z, V0.w, V1.x, V1.y, V1.z, V1.w};    \
    union { uint4v u; bf16x8 b; } ah, al;                             \
    _Pragma("unroll")                                                 \
    for (int q = 0; q < 4; ++q) {                                     \
      unsigned ua = __float_as_uint(f[2 * q]);                        \
      unsigned ub = __float_as_uint(f[2 * q + 1]);                    \
      ah.u[q] = __builtin_amdgcn_perm(ub, ua, 0x07060302u);           \
      float ra = f[2 * q]     - __uint_as_float(ua & 0xFFFF0000u);    \
      float rb = f[2 * q + 1] - __uint_as_float(ub & 0xFFFF0000u);    \
      al.u[q] = __builtin_amdgcn_perm(__float_as_uint(rb),            \
                                      __float_as_uint(ra),            \
                                      0x07060302u);                   \
    }                                                                 \
    _Pragma("unroll")                                                 \
    for (int ct = 0; ct < 4; ++ct) {                                  \
      acc[RT][ct] = __builtin_amdgcn_mfma_f32_16x16x32_bf16(          \
          ah.b, bh[ct], acc[RT][ct], 0, 0, 0);                        \
      acc[RT][ct] = __builtin_amdgcn_mfma_f32_16x16x32_bf16(          \
          ah.b, bl[ct], acc[RT][ct], 0, 0, 0);                        \
      acc[RT][ct] = __builtin_amdgcn_mfma_f32_16x16x32_bf16(          \
          al.b, bh[ct], acc[RT][ct], 0, 0, 0);                        \
    }                                                                 \
  } while (0)

__global__ __launch_bounds__(256) void mlp_kernel(
    const float* __restrict__ x,
    const unsigned short* __restrict__ whT, const unsigned short* __restrict__ wlT,
    const float* __restrict__ b1, const float* __restrict__ W2,
    const float* __restrict__ b2, float* __restrict__ yv,
    float* __restrict__ zv, int N) {
  __shared__ float redy[128][2];
  __shared__ float redz[128][2];

  const int t = threadIdx.x;
  const int lane = t & 63;
  const int w = t >> 6;
  const int wr = w >> 1, wc = w & 1;           // wave grid 2x2
  const int ln15 = lane & 15, lq = lane >> 4;  // quad

  const int row0 = blockIdx.x * 128;

  f32x4 acc[4][4];  // [rt][ct]
#pragma unroll
  for (int i = 0; i < 4; ++i)
#pragma unroll
    for (int j = 0; j < 4; ++j) acc[i][j] = (f32x4){0.f, 0.f, 0.f, 0.f};

  bool rv[4];
  const float* xb[4];
#pragma unroll
  for (int rt = 0; rt < 4; ++rt) {
    int rowg = row0 + wr * 64 + rt * 16 + ln15;
    rv[rt] = rowg < N;
    xb[rt] = x + (size_t)rowg * F + lq * 8;    // +kc*32 folds to imm offset
  }
  const int cbase = wc * 64 + ln15;            // + ct*16
  const unsigned short* wb = whT + cbase * 32 + lq * 8;
  const unsigned short* lb = wlT + cbase * 32 + lq * 8;

  float4 pa0[2], pa1[2];                       // rt0, rt1 fragments
  float4 qa0[2], qa1[2];                       // rt2, rt3 fragments
  LOADP(0);
  LOADQ(0);

  for (int kc = 0; kc < 8; ++kc) {
    bf16x8 bh[4], bl[4];
#pragma unroll
    for (int ct = 0; ct < 4; ++ct) {
      bh[ct] = *(const bf16x8*)(wb + kc * 4096 + ct * 512);
      bl[ct] = *(const bf16x8*)(lb + kc * 4096 + ct * 512);
    }
    // consume P (rt0, rt1), then refill for kc+1 while Q computes
    SPLIT_MFMA(pa0[0], pa1[0], 0);
    SPLIT_MFMA(pa0[1], pa1[1], 1);
    if (kc < 7) LOADP(kc + 1);
    // consume Q (rt2, rt3), then refill for kc+1 while next kc's B+P compute
    SPLIT_MFMA(qa0[0], qa1[0], 2);
    SPLIT_MFMA(qa0[1], qa1[1], 3);
    if (kc < 7) LOADQ(kc + 1);
  }

  // ---- epilogue: h = tanh(acc + b1), contract with W2 ----
  // acc[rt][ct][rg]: row = wr*64+rt*16+lq*4+rg, col = wc*64+ct*16+ln15
  float yp[4][4], zp[4][4];
#pragma unroll
  for (int i = 0; i < 4; ++i)
#pragma unroll
    for (int j = 0; j < 4; ++j) { yp[i][j] = 0.f; zp[i][j] = 0.f; }
#pragma unroll
  for (int ct = 0; ct < 4; ++ct) {
    int c = cbase + ct * 16;
    float b1c = b1[c], wyc = W2[2 * c], wzc = W2[2 * c + 1];
#pragma unroll
    for (int rt = 0; rt < 4; ++rt)
#pragma unroll
      for (int rg = 0; rg < 4; ++rg) {
        float a = acc[rt][ct][rg] + b1c;
        float e = __expf(2.f * a);
        float h = 1.f - __fdividef(2.f, e + 1.f);   // tanh(a)
        yp[rt][rg] = fmaf(h, wyc, yp[rt][rg]);
        zp[rt][rg] = fmaf(h, wzc, zp[rt][rg]);
      }
  }
#pragma unroll
  for (int rt = 0; rt < 4; ++rt)
#pragma unroll
    for (int rg = 0; rg < 4; ++rg) {
      float vy = yp[rt][rg], vz = zp[rt][rg];
#pragma unroll
      for (int m = 8; m; m >>= 1) {
        vy += __shfl_xor(vy, m);
        vz += __shfl_xor(vz, m);
      }
      if (ln15 == 0) {
        int row = wr * 64 + rt * 16 + lq * 4 + rg;
        redy[row][wc] = vy;
        redz[row][wc] = vz;
      }
    }
  __syncthreads();
  if (t < 128) {
    int g = row0 + t;
    if (g < N) {
      yv[g] = redy[t][0] + redy[t][1] + b2[0];
      zv[g] = redz[t][0] + redz[t][1] + b2[1];
    }
  }
}
#undef LOADP
#undef LOADQ
#undef SPLIT_MFMA

// ---------------------------------------------------------------------------
// K2 (fused stats+pool), unchanged from round-4 (nchunks=8; measured equal
// to round-2's separate stats+pool32 within noise, one fewer dispatch).
// Keeps reverse-stream L3 harvest ordering.
// ---------------------------------------------------------------------------
__device__ inline float wave_reduce_sum(float v) {
#pragma unroll
  for (int o = 32; o; o >>= 1) v += __shfl_down(v, o);
  return v;
}
__device__ inline float wave_reduce_max(float v) {
#pragma unroll
  for (int o = 32; o; o >>= 1) v = fmaxf(v, __shfl_down(v, o));
  return v;
}

__global__ __launch_bounds__(256) void pool_kernel(
    const float* __restrict__ x,
    const float* __restrict__ yv, const float* __restrict__ zv,
    const int* __restrict__ offsets, const int* __restrict__ lengths,
    float* __restrict__ attn, float* __restrict__ out,
    int nchunks, int S) {
  __shared__ float ybuf[MAXL];         // 12 KB
  __shared__ float4 sbuf[4][64];       // 4 KB
  __shared__ float redA[4], redB[4], redC[4];

  const int s = S - 1 - blockIdx.y;
  const int c = nchunks - 1 - blockIdx.x;
  const int off = offsets[s], L = lengths[s];
  const int t = threadIdx.x;
  const int lane = t & 63, wid = t >> 6;   // 4 waves

  // ---- phase 1: stage y, running max ----
  float lmax = -1e30f;
  for (int i = t; i < L; i += 256) {
    float yy = yv[off + i];
    ybuf[i] = yy;
    lmax = fmaxf(lmax, yy);
  }
  lmax = wave_reduce_max(lmax);
  if (lane == 0) redA[wid] = lmax;
  __syncthreads();
  const float ymax = fmaxf(fmaxf(redA[0], redA[1]), fmaxf(redA[2], redA[3]));
  const float invL = 1.f / (float)L;
  __syncthreads();   // protect redA before reuse

  // ---- phase 2: weighted sums ----
  float sw = 0.f, smx = 0.f, sz = 0.f;
  for (int i = t; i < L; i += 256) {
    float wgt = __expf(ybuf[i] - ymax);
    float xp = (float)(i + 1) * invL;
    sw += wgt;
    smx = fmaf(xp, wgt, smx);
    sz += zv[off + i];
  }
  sw = wave_reduce_sum(sw);
  smx = wave_reduce_sum(smx);
  sz = wave_reduce_sum(sz);
  if (lane == 0) { redA[wid] = sw; redB[wid] = smx; redC[wid] = sz; }
  __syncthreads();
  const float wsum = (redA[0] + redA[1]) + (redA[2] + redA[3]);
  const float mxs  = (redB[0] + redB[1]) + (redB[2] + redB[3]);
  const float zsum = (redC[0] + redC[1]) + (redC[2] + redC[3]);
  const float mu = mxs / wsum;
  const float tz = zsum * invL;
  const float sd = fmaxf(tz, 0.f) + log1pf(__expf(-fabsf(tz)));  // softplus
  const float invsd = 1.f / sd;
  const float Cg = 0.3989422804014327f;  // 1/sqrt(2*pi)
  __syncthreads();   // protect redA before reuse

  // ---- phase 3: psum over FULL segment (pure function of i, L, mu, sd) ----
  float ps = 0.f;
  for (int i = t; i < L; i += 256) {
    float xp = (float)(i + 1) * invL;
    float u = (xp - mu) * invsd;
    ps += __expf(-0.5f * u * u);
  }
  ps = wave_reduce_sum(ps);
  if (lane == 0) redA[wid] = ps;
  __syncthreads();
  const float psum = ((redA[0] + redA[1]) + (redA[2] + redA[3])) * (Cg * invsd);
  const float scale = (Cg * invsd) / (psum + 0.001f);   // attn_i = exp(-u^2/2)*scale

  // ---- phase 4: write attn for own chunk (coalesced) ----
  const int i0 = (int)((long long)L * c / nchunks);
  const int i1 = (int)((long long)L * (c + 1) / nchunks);
  for (int i = i0 + t; i < i1; i += 256) {
    float xp = (float)(i + 1) * invL;
    float u = (xp - mu) * invsd;
    attn[off + i] = __expf(-0.5f * u * u) * scale;
  }

  // ---- phase 5: pool own chunk of x, descending rows (L3 harvest) ----
  float4 a0 = make_float4(0.f, 0.f, 0.f, 0.f);
  float4 a1 = make_float4(0.f, 0.f, 0.f, 0.f);
  int i = i1 - 1 - wid;
  for (; i - 4 >= i0; i -= 8) {
    float xpa = (float)(i + 1) * invL;
    float ua = (xpa - mu) * invsd;
    float w0 = __expf(-0.5f * ua * ua) * scale;
    float xpb = (float)(i - 3) * invL;
    float ub = (xpb - mu) * invsd;
    float w1 = __expf(-0.5f * ub * ub) * scale;
    float4 v0 = *(const float4*)&x[(size_t)(off + i) * F + lane * 4];
    float4 v1 = *(const float4*)&x[(size_t)(off + i - 4) * F + lane * 4];
    a0.x = fmaf(w0, v0.x, a0.x); a0.y = fmaf(w0, v0.y, a0.y);
    a0.z = fmaf(w0, v0.z, a0.z); a0.w = fmaf(w0, v0.w, a0.w);
    a1.x = fmaf(w1, v1.x, a1.x); a1.y = fmaf(w1, v1.y, a1.y);
    a1.z = fmaf(w1, v1.z, a1.z); a1.w = fmaf(w1, v1.w, a1.w);
  }
  if (i >= i0) {
    float xpa = (float)(i + 1) * invL;
    float ua = (xpa - mu) * invsd;
    float w0 = __expf(-0.5f * ua * ua) * scale;
    float4 v0 = *(const float4*)&x[(size_t)(off + i) * F + lane * 4];
    a0.x = fmaf(w0, v0.x, a0.x); a0.y = fmaf(w0, v0.y, a0.y);
    a0.z = fmaf(w0, v0.z, a0.z); a0.w = fmaf(w0, v0.w, a0.w);
  }
  a0.x += a1.x; a0.y += a1.y; a0.z += a1.z; a0.w += a1.w;
  sbuf[wid][lane] = a0;
  __syncthreads();
  if (wid == 0) {
    float4 r0 = sbuf[0][lane], r1 = sbuf[1][lane];
    float4 r2 = sbuf[2][lane], r3 = sbuf[3][lane];
    float rx = (r0.x + r1.x) + (r2.x + r3.x);
    float ry = (r0.y + r1.y) + (r2.y + r3.y);
    float rz = (r0.z + r1.z) + (r2.z + r3.z);
    float rw = (r0.w + r1.w) + (r2.w + r3.w);
    float* o = &out[s * F + lane * 4];
    atomicAdd(o + 0, rx);
    atomicAdd(o + 1, ry);
    atomicAdd(o + 2, rz);
    atomicAdd(o + 3, rw);
  }
}

// ---------------------------------------------------------------------------
extern "C" void kernel_launch(void* const* d_in, const int* in_sizes, int n_in,
                              void* d_out, int out_size, void* d_ws, size_t ws_size,
                              hipStream_t stream) {
  const float* x      = (const float*)d_in[0];
  const int* lengths  = (const int*)d_in[1];
  const float* W1     = (const float*)d_in[2];
  const float* b1     = (const float*)d_in[3];
  const float* W2     = (const float*)d_in[4];
  const float* b2     = (const float*)d_in[5];
  const int S = in_sizes[1];
  const int N = in_sizes[0] / F;

  float* out  = (float*)d_out;             // S*F
  float* attn = out + (size_t)S * F;       // N

  int*   offsets = (int*)d_ws;                       // 512 ints (2 KB)
  float* yv = (float*)d_ws + 512;                    // N floats
  float* zv = yv + N;                                // N floats
  unsigned short* whT = (unsigned short*)(zv + N);   // 32768 shorts (64 KB)
  unsigned short* wlT = whT + F * Hh;                // 32768 shorts (64 KB)

  init_kernel<<<64, 256, 0, stream>>>(lengths, offsets, out, W1, whT, wlT, S, S * F);
  mlp_kernel<<<(N + 127) / 128, 256, 0, stream>>>(x, whT, wlT, b1, W2, b2, yv, zv, N);
  pool_kernel<<<dim3(8, S), 256, 0, stream>>>(x, yv, zv, offsets, lengths, attn, out, 8, S);
}

// Round 6
// 463.254 us; speedup vs baseline: 1.0417x; 1.0200x over previous
//
#include <hip/hip_runtime.h>
#include <math.h>

#define F 256
#define Hh 128
#define MAXL 3072

typedef short bf16x8 __attribute__((ext_vector_type(8)));
typedef float f32x4 __attribute__((ext_vector_type(4)));
typedef unsigned int uint4v __attribute__((ext_vector_type(4)));

__device__ inline unsigned short f2bf_rne(float f) {
  unsigned u = __float_as_uint(f);
  unsigned r = u + 0x7fff + ((u >> 16) & 1);
  return (unsigned short)(r >> 16);
}
__device__ inline float bf2f(unsigned short h) {
  return __uint_as_float((unsigned)h << 16);
}

// ---------------------------------------------------------------------------
// K0: zero out, prefix-scan lengths, split W1 into bf16 hi/lo transposed
// chunk-major:  whT[chunk][col][k]  (chunk = k/32, k local 0..31), 8 chunks.
// ---------------------------------------------------------------------------
__global__ void init_kernel(const int* __restrict__ lengths, int* __restrict__ offsets,
                            float* __restrict__ out, const float* __restrict__ W1,
                            unsigned short* __restrict__ whT, unsigned short* __restrict__ wlT,
                            int S, int outN) {
  int t = blockIdx.x * blockDim.x + threadIdx.x;
  int stride = gridDim.x * blockDim.x;
  for (int i = t; i < outN; i += stride) out[i] = 0.f;
  for (int i = t; i < F * Hh; i += stride) {
    int k = i >> 7, col = i & 127;
    float v = W1[i];
    unsigned short h = f2bf_rne(v);
    unsigned short l = f2bf_rne(v - bf2f(h));
    int dst = (k >> 5) * (128 * 32) + col * 32 + (k & 31);
    whT[dst] = h;
    wlT[dst] = l;
  }
  if (blockIdx.x == 0) {
    __shared__ int buf[256];
    int tid = threadIdx.x;
    int v = (tid < S) ? lengths[tid] : 0;
    buf[tid] = v;
    __syncthreads();
    for (int o = 1; o < 256; o <<= 1) {
      int add = (tid >= o) ? buf[tid - o] : 0;
      __syncthreads();
      buf[tid] += add;
      __syncthreads();
    }
    if (tid < S) offsets[tid] = buf[tid] - v;   // exclusive
    if (tid == S - 1) offsets[S] = buf[tid];    // total N
  }
}

// ---------------------------------------------------------------------------
// K1: fused MLP via MFMA.  STRUCTURE CHANGE (m97 pattern): x is staged
// per-kc into LDS via global_load_lds width=16 (async, no VGPR round-trip,
// 8x128B contiguous segments per wave instead of 16x64B scatter per load),
// double-buffered 2-phase: STAGE(kc+1) || compute(kc); one barrier per kc.
// LDS layout XOR-swizzled  byte ^= ((row&7)<<4)  applied BOTH sides
// (pre-swizzled global source + swizzled ds_read) per rule 21; without it
// the 128B row stride is a 16-way bank conflict on ds_read_b128.
// Fragment values / split math / MFMA sequence bitwise-identical to the
// round-0 form (146us measured) -> absmax must stay 6.1e-5.
// Register-level reschedules (r1/r4/r5) all failed; this attacks the VMEM
// scatter + latency chain instead.
// ---------------------------------------------------------------------------
#define STAGE(B, KC) do {                                               \
    _Pragma("unroll")                                                   \
    for (int r = 0; r < 4; ++r) {                                       \
      __builtin_amdgcn_global_load_lds(                                 \
          (const __attribute__((address_space(1))) unsigned int*)       \
              (srow[r] + (KC) * 32),                                    \
          (__attribute__((address_space(3))) unsigned int*)             \
              (xs + (B) * 4096 + r * 1024 + t * 4),                     \
          16, 0, 0);                                                    \
    }                                                                   \
  } while (0)

// truncation split of 8 f32 -> bf16 hi/lo + 3 MFMA passes for one rt
#define SPLIT_MFMA(V0, V1, RT) do {                                     \
    float f[8] = {V0.x, V0.y, V0.z, V0.w, V1.x, V1.y, V1.z, V1.w};      \
    union { uint4v u; bf16x8 b; } ah, al;                               \
    _Pragma("unroll")                                                   \
    for (int q = 0; q < 4; ++q) {                                       \
      unsigned ua = __float_as_uint(f[2 * q]);                          \
      unsigned ub = __float_as_uint(f[2 * q + 1]);                      \
      ah.u[q] = __builtin_amdgcn_perm(ub, ua, 0x07060302u);             \
      float ra = f[2 * q]     - __uint_as_float(ua & 0xFFFF0000u);      \
      float rb = f[2 * q + 1] - __uint_as_float(ub & 0xFFFF0000u);      \
      al.u[q] = __builtin_amdgcn_perm(__float_as_uint(rb),              \
                                      __float_as_uint(ra),              \
                                      0x07060302u);                     \
    }                                                                   \
    _Pragma("unroll")                                                   \
    for (int ct = 0; ct < 4; ++ct) {                                    \
      acc[RT][ct] = __builtin_amdgcn_mfma_f32_16x16x32_bf16(            \
          ah.b, bh[ct], acc[RT][ct], 0, 0, 0);                          \
      acc[RT][ct] = __builtin_amdgcn_mfma_f32_16x16x32_bf16(            \
          ah.b, bl[ct], acc[RT][ct], 0, 0, 0);                          \
      acc[RT][ct] = __builtin_amdgcn_mfma_f32_16x16x32_bf16(            \
          al.b, bh[ct], acc[RT][ct], 0, 0, 0);                          \
    }                                                                   \
  } while (0)

__global__ __launch_bounds__(256) void mlp_kernel(
    const float* __restrict__ x,
    const unsigned short* __restrict__ whT, const unsigned short* __restrict__ wlT,
    const float* __restrict__ b1, const float* __restrict__ W2,
    const float* __restrict__ b2, float* __restrict__ yv,
    float* __restrict__ zv, int N) {
  __shared__ float xs[2 * 4096];       // 2 x 16KB kc-tiles of x
  __shared__ float redy[128][2];
  __shared__ float redz[128][2];

  const int t = threadIdx.x;
  const int lane = t & 63;
  const int w = t >> 6;
  const int wr = w >> 1, wc = w & 1;           // wave grid 2x2
  const int ln15 = lane & 15, lq = lane >> 4;  // quad

  const int row0 = blockIdx.x * 128;

  f32x4 acc[4][4];  // [rt][ct]
#pragma unroll
  for (int i = 0; i < 4; ++i)
#pragma unroll
    for (int j = 0; j < 4; ++j) acc[i][j] = (f32x4){0.f, 0.f, 0.f, 0.f};

  // ---- staging source pointers (per thread, kc-invariant) ----
  // round r stages LDS rows [r*32, r*32+32); thread covers row r*32+(t>>3),
  // physical 16B slot (t&7).  Physical slot p holds LOGICAL col (p ^ swz),
  // so the global source col is pre-swizzled (rule 21: swizzle both sides).
  const float* srow[4];
  {
    const int rsub = t >> 3;                   // row within 32-row group
    const int swzs = (rsub & 7) << 4;          // row&7 == (t>>3)&7 for all r
    const int scolb = ((t & 7) * 16) ^ swzs;   // pre-swizzled source byte col
#pragma unroll
    for (int r = 0; r < 4; ++r) {
      int grow = row0 + r * 32 + rsub;
      grow = grow < N ? grow : N - 1;          // clamp: rows >=N computed, never stored
      srow[r] = x + (size_t)grow * F + (scolb >> 2);
    }
  }

  // ---- LDS read offsets (per thread, kc-invariant): logical col c of row
  // is at physical byte  row*128 + (c ^ ((row&7)<<4)) ----
  const int row_l = wr * 64 + ln15;            // + rt*16
  const int swzr = (ln15 & 7) << 4;            // row_l&7 == ln15&7
  const int p0base = row_l * 128 + ((lq * 32) ^ swzr);   // + rt*2048

  const int cbase = wc * 64 + ln15;            // + ct*16
  const unsigned short* wb = whT + cbase * 32 + lq * 8;
  const unsigned short* lb = wlT + cbase * 32 + lq * 8;

  STAGE(0, 0);
  __syncthreads();                             // drains vmcnt: buf0 ready

#pragma unroll
  for (int kc = 0; kc < 8; ++kc) {
    if (kc < 7) STAGE((kc + 1) & 1, kc + 1);   // async prefetch next tile
    bf16x8 bh[4], bl[4];
#pragma unroll
    for (int ct = 0; ct < 4; ++ct) {
      bh[ct] = *(const bf16x8*)(wb + kc * 4096 + ct * 512);
      bl[ct] = *(const bf16x8*)(lb + kc * 4096 + ct * 512);
    }
    const char* bufp = (const char*)xs + (kc & 1) * 16384;
#pragma unroll
    for (int rt = 0; rt < 4; ++rt) {
      // logical low half at p0, logical high half at p0^16 (swizzle XOR)
      const int p0 = p0base + rt * 2048;
      float4 lo = *(const float4*)(bufp + p0);
      float4 hi = *(const float4*)(bufp + (p0 ^ 16));
      SPLIT_MFMA(lo, hi, rt);
    }
    __syncthreads();   // all reads of buf[kc&1] done + STAGE(kc+1) drained
  }

  // ---- epilogue: h = tanh(acc + b1), contract with W2 ----
  // acc[rt][ct][rg]: row = wr*64+rt*16+lq*4+rg, col = wc*64+ct*16+ln15
  float yp[4][4], zp[4][4];
#pragma unroll
  for (int i = 0; i < 4; ++i)
#pragma unroll
    for (int j = 0; j < 4; ++j) { yp[i][j] = 0.f; zp[i][j] = 0.f; }
#pragma unroll
  for (int ct = 0; ct < 4; ++ct) {
    int c = cbase + ct * 16;
    float b1c = b1[c], wyc = W2[2 * c], wzc = W2[2 * c + 1];
#pragma unroll
    for (int rt = 0; rt < 4; ++rt)
#pragma unroll
      for (int rg = 0; rg < 4; ++rg) {
        float a = acc[rt][ct][rg] + b1c;
        float e = __expf(2.f * a);
        float h = 1.f - __fdividef(2.f, e + 1.f);   // tanh(a)
        yp[rt][rg] = fmaf(h, wyc, yp[rt][rg]);
        zp[rt][rg] = fmaf(h, wzc, zp[rt][rg]);
      }
  }
#pragma unroll
  for (int rt = 0; rt < 4; ++rt)
#pragma unroll
    for (int rg = 0; rg < 4; ++rg) {
      float vy = yp[rt][rg], vz = zp[rt][rg];
#pragma unroll
      for (int m = 8; m; m >>= 1) {
        vy += __shfl_xor(vy, m);
        vz += __shfl_xor(vz, m);
      }
      if (ln15 == 0) {
        int row = wr * 64 + rt * 16 + lq * 4 + rg;
        redy[row][wc] = vy;
        redz[row][wc] = vz;
      }
    }
  __syncthreads();
  if (t < 128) {
    int g = row0 + t;
    if (g < N) {
      yv[g] = redy[t][0] + redy[t][1] + b2[0];
      zv[g] = redz[t][0] + redz[t][1] + b2[1];
    }
  }
}
#undef STAGE
#undef SPLIT_MFMA

// ---------------------------------------------------------------------------
// K2 (fused stats+pool), unchanged (nchunks=8, reverse-stream L3 harvest).
// ---------------------------------------------------------------------------
__device__ inline float wave_reduce_sum(float v) {
#pragma unroll
  for (int o = 32; o; o >>= 1) v += __shfl_down(v, o);
  return v;
}
__device__ inline float wave_reduce_max(float v) {
#pragma unroll
  for (int o = 32; o; o >>= 1) v = fmaxf(v, __shfl_down(v, o));
  return v;
}

__global__ __launch_bounds__(256) void pool_kernel(
    const float* __restrict__ x,
    const float* __restrict__ yv, const float* __restrict__ zv,
    const int* __restrict__ offsets, const int* __restrict__ lengths,
    float* __restrict__ attn, float* __restrict__ out,
    int nchunks, int S) {
  __shared__ float ybuf[MAXL];         // 12 KB
  __shared__ float4 sbuf[4][64];       // 4 KB
  __shared__ float redA[4], redB[4], redC[4];

  const int s = S - 1 - blockIdx.y;
  const int c = nchunks - 1 - blockIdx.x;
  const int off = offsets[s], L = lengths[s];
  const int t = threadIdx.x;
  const int lane = t & 63, wid = t >> 6;   // 4 waves

  // ---- phase 1: stage y, running max ----
  float lmax = -1e30f;
  for (int i = t; i < L; i += 256) {
    float yy = yv[off + i];
    ybuf[i] = yy;
    lmax = fmaxf(lmax, yy);
  }
  lmax = wave_reduce_max(lmax);
  if (lane == 0) redA[wid] = lmax;
  __syncthreads();
  const float ymax = fmaxf(fmaxf(redA[0], redA[1]), fmaxf(redA[2], redA[3]));
  const float invL = 1.f / (float)L;
  __syncthreads();   // protect redA before reuse

  // ---- phase 2: weighted sums ----
  float sw = 0.f, smx = 0.f, sz = 0.f;
  for (int i = t; i < L; i += 256) {
    float wgt = __expf(ybuf[i] - ymax);
    float xp = (float)(i + 1) * invL;
    sw += wgt;
    smx = fmaf(xp, wgt, smx);
    sz += zv[off + i];
  }
  sw = wave_reduce_sum(sw);
  smx = wave_reduce_sum(smx);
  sz = wave_reduce_sum(sz);
  if (lane == 0) { redA[wid] = sw; redB[wid] = smx; redC[wid] = sz; }
  __syncthreads();
  const float wsum = (redA[0] + redA[1]) + (redA[2] + redA[3]);
  const float mxs  = (redB[0] + redB[1]) + (redB[2] + redB[3]);
  const float zsum = (redC[0] + redC[1]) + (redC[2] + redC[3]);
  const float mu = mxs / wsum;
  const float tz = zsum * invL;
  const float sd = fmaxf(tz, 0.f) + log1pf(__expf(-fabsf(tz)));  // softplus
  const float invsd = 1.f / sd;
  const float Cg = 0.3989422804014327f;  // 1/sqrt(2*pi)
  __syncthreads();   // protect redA before reuse

  // ---- phase 3: psum over FULL segment (pure function of i, L, mu, sd) ----
  float ps = 0.f;
  for (int i = t; i < L; i += 256) {
    float xp = (float)(i + 1) * invL;
    float u = (xp - mu) * invsd;
    ps += __expf(-0.5f * u * u);
  }
  ps = wave_reduce_sum(ps);
  if (lane == 0) redA[wid] = ps;
  __syncthreads();
  const float psum = ((redA[0] + redA[1]) + (redA[2] + redA[3])) * (Cg * invsd);
  const float scale = (Cg * invsd) / (psum + 0.001f);   // attn_i = exp(-u^2/2)*scale

  // ---- phase 4: write attn for own chunk (coalesced) ----
  const int i0 = (int)((long long)L * c / nchunks);
  const int i1 = (int)((long long)L * (c + 1) / nchunks);
  for (int i = i0 + t; i < i1; i += 256) {
    float xp = (float)(i + 1) * invL;
    float u = (xp - mu) * invsd;
    attn[off + i] = __expf(-0.5f * u * u) * scale;
  }

  // ---- phase 5: pool own chunk of x, descending rows (L3 harvest) ----
  float4 a0 = make_float4(0.f, 0.f, 0.f, 0.f);
  float4 a1 = make_float4(0.f, 0.f, 0.f, 0.f);
  int i = i1 - 1 - wid;
  for (; i - 4 >= i0; i -= 8) {
    float xpa = (float)(i + 1) * invL;
    float ua = (xpa - mu) * invsd;
    float w0 = __expf(-0.5f * ua * ua) * scale;
    float xpb = (float)(i - 3) * invL;
    float ub = (xpb - mu) * invsd;
    float w1 = __expf(-0.5f * ub * ub) * scale;
    float4 v0 = *(const float4*)&x[(size_t)(off + i) * F + lane * 4];
    float4 v1 = *(const float4*)&x[(size_t)(off + i - 4) * F + lane * 4];
    a0.x = fmaf(w0, v0.x, a0.x); a0.y = fmaf(w0, v0.y, a0.y);
    a0.z = fmaf(w0, v0.z, a0.z); a0.w = fmaf(w0, v0.w, a0.w);
    a1.x = fmaf(w1, v1.x, a1.x); a1.y = fmaf(w1, v1.y, a1.y);
    a1.z = fmaf(w1, v1.z, a1.z); a1.w = fmaf(w1, v1.w, a1.w);
  }
  if (i >= i0) {
    float xpa = (float)(i + 1) * invL;
    float ua = (xpa - mu) * invsd;
    float w0 = __expf(-0.5f * ua * ua) * scale;
    float4 v0 = *(const float4*)&x[(size_t)(off + i) * F + lane * 4];
    a0.x = fmaf(w0, v0.x, a0.x); a0.y = fmaf(w0, v0.y, a0.y);
    a0.z = fmaf(w0, v0.z, a0.z); a0.w = fmaf(w0, v0.w, a0.w);
  }
  a0.x += a1.x; a0.y += a1.y; a0.z += a1.z; a0.w += a1.w;
  sbuf[wid][lane] = a0;
  __syncthreads();
  if (wid == 0) {
    float4 r0 = sbuf[0][lane], r1 = sbuf[1][lane];
    float4 r2 = sbuf[2][lane], r3 = sbuf[3][lane];
    float rx = (r0.x + r1.x) + (r2.x + r3.x);
    float ry = (r0.y + r1.y) + (r2.y + r3.y);
    float rz = (r0.z + r1.z) + (r2.z + r3.z);
    float rw = (r0.w + r1.w) + (r2.w + r3.w);
    float* o = &out[s * F + lane * 4];
    atomicAdd(o + 0, rx);
    atomicAdd(o + 1, ry);
    atomicAdd(o + 2, rz);
    atomicAdd(o + 3, rw);
  }
}

// ---------------------------------------------------------------------------
extern "C" void kernel_launch(void* const* d_in, const int* in_sizes, int n_in,
                              void* d_out, int out_size, void* d_ws, size_t ws_size,
                              hipStream_t stream) {
  const float* x      = (const float*)d_in[0];
  const int* lengths  = (const int*)d_in[1];
  const float* W1     = (const float*)d_in[2];
  const float* b1     = (const float*)d_in[3];
  const float* W2     = (const float*)d_in[4];
  const float* b2     = (const float*)d_in[5];
  const int S = in_sizes[1];
  const int N = in_sizes[0] / F;

  float* out  = (float*)d_out;             // S*F
  float* attn = out + (size_t)S * F;       // N

  int*   offsets = (int*)d_ws;                       // 512 ints (2 KB)
  float* yv = (float*)d_ws + 512;                    // N floats
  float* zv = yv + N;                                // N floats
  unsigned short* whT = (unsigned short*)(zv + N);   // 32768 shorts (64 KB)
  unsigned short* wlT = whT + F * Hh;                // 32768 shorts (64 KB)

  init_kernel<<<64, 256, 0, stream>>>(lengths, offsets, out, W1, whT, wlT, S, S * F);
  mlp_kernel<<<(N + 127) / 128, 256, 0, stream>>>(x, whT, wlT, b1, W2, b2, yv, zv, N);
  pool_kernel<<<dim3(8, S), 256, 0, stream>>>(x, yv, zv, offsets, lengths, attn, out, 8, S);
}

// Round 7
// 442.095 us; speedup vs baseline: 1.0916x; 1.0479x over previous
//
#include <hip/hip_runtime.h>
#include <math.h>

#define F 256
#define Hh 128
#define MAXL 3072

typedef short bf16x8 __attribute__((ext_vector_type(8)));
typedef float f32x4 __attribute__((ext_vector_type(4)));
typedef unsigned int uint4v __attribute__((ext_vector_type(4)));

__device__ inline unsigned short f2bf_rne(float f) {
  unsigned u = __float_as_uint(f);
  unsigned r = u + 0x7fff + ((u >> 16) & 1);
  return (unsigned short)(r >> 16);
}
__device__ inline float bf2f(unsigned short h) {
  return __uint_as_float((unsigned)h << 16);
}

// ---------------------------------------------------------------------------
// K0: zero out, prefix-scan lengths, split W1 into bf16 hi/lo transposed
// chunk-major:  whT[chunk][col][k]  (chunk = k/32, k local 0..31), 8 chunks.
// ---------------------------------------------------------------------------
__global__ void init_kernel(const int* __restrict__ lengths, int* __restrict__ offsets,
                            float* __restrict__ out, const float* __restrict__ W1,
                            unsigned short* __restrict__ whT, unsigned short* __restrict__ wlT,
                            int S, int outN) {
  int t = blockIdx.x * blockDim.x + threadIdx.x;
  int stride = gridDim.x * blockDim.x;
  for (int i = t; i < outN; i += stride) out[i] = 0.f;
  for (int i = t; i < F * Hh; i += stride) {
    int k = i >> 7, col = i & 127;
    float v = W1[i];
    unsigned short h = f2bf_rne(v);
    unsigned short l = f2bf_rne(v - bf2f(h));
    int dst = (k >> 5) * (128 * 32) + col * 32 + (k & 31);
    whT[dst] = h;
    wlT[dst] = l;
  }
  if (blockIdx.x == 0) {
    __shared__ int buf[256];
    int tid = threadIdx.x;
    int v = (tid < S) ? lengths[tid] : 0;
    buf[tid] = v;
    __syncthreads();
    for (int o = 1; o < 256; o <<= 1) {
      int add = (tid >= o) ? buf[tid - o] : 0;
      __syncthreads();
      buf[tid] += add;
      __syncthreads();
    }
    if (tid < S) offsets[tid] = buf[tid] - v;   // exclusive
    if (tid == S - 1) offsets[S] = buf[tid];    // total N
  }
}

// ---------------------------------------------------------------------------
// K1: fused MLP via MFMA, LDS-staged x (r6 structure) + THIS ROUND:
// counted-vmcnt barrier discipline (T4).  r6 ended each kc with
// __syncthreads() = s_waitcnt vmcnt(0) + barrier, draining the kc+1
// prefetch every iteration (the m97-ceiling structure).  Now:
//   B-loads(kc) -> STAGE(kc+1) -> s_waitcnt vmcnt(4) -> s_barrier
//   -> compute -> s_barrier
// vmcnt(4): in-order retirement => <=4 outstanding means the 4 newest
// (STAGE(kc+1)) may still fly while STAGE(kc)+B(kc) are done.  The
// prefetch now spans the whole compute phase; no vmcnt(0) in the loop.
// Raw barriers carry "memory" clobbers; ds_reads/STAGE are memory ops so
// ordering holds (rule-18 hazard is register-only asm, not present here).
// Math bitwise-identical to r0/r6 -> absmax must stay 6.103516e-05.
// ---------------------------------------------------------------------------
#define STAGE(B, KC) do {                                               \
    _Pragma("unroll")                                                   \
    for (int r = 0; r < 4; ++r) {                                       \
      __builtin_amdgcn_global_load_lds(                                 \
          (const __attribute__((address_space(1))) unsigned int*)       \
              (srow[r] + (KC) * 32),                                    \
          (__attribute__((address_space(3))) unsigned int*)             \
              (xs + (B) * 4096 + r * 1024 + t * 4),                     \
          16, 0, 0);                                                    \
    }                                                                   \
  } while (0)

// truncation split of 8 f32 -> bf16 hi/lo + 3 MFMA passes for one rt
#define SPLIT_MFMA(V0, V1, RT) do {                                     \
    float f[8] = {V0.x, V0.y, V0.z, V0.w, V1.x, V1.y, V1.z, V1.w};      \
    union { uint4v u; bf16x8 b; } ah, al;                               \
    _Pragma("unroll")                                                   \
    for (int q = 0; q < 4; ++q) {                                       \
      unsigned ua = __float_as_uint(f[2 * q]);                          \
      unsigned ub = __float_as_uint(f[2 * q + 1]);                      \
      ah.u[q] = __builtin_amdgcn_perm(ub, ua, 0x07060302u);             \
      float ra = f[2 * q]     - __uint_as_float(ua & 0xFFFF0000u);      \
      float rb = f[2 * q + 1] - __uint_as_float(ub & 0xFFFF0000u);      \
      al.u[q] = __builtin_amdgcn_perm(__float_as_uint(rb),              \
                                      __float_as_uint(ra),              \
                                      0x07060302u);                     \
    }                                                                   \
    _Pragma("unroll")                                                   \
    for (int ct = 0; ct < 4; ++ct) {                                    \
      acc[RT][ct] = __builtin_amdgcn_mfma_f32_16x16x32_bf16(            \
          ah.b, bh[ct], acc[RT][ct], 0, 0, 0);                          \
      acc[RT][ct] = __builtin_amdgcn_mfma_f32_16x16x32_bf16(            \
          ah.b, bl[ct], acc[RT][ct], 0, 0, 0);                          \
      acc[RT][ct] = __builtin_amdgcn_mfma_f32_16x16x32_bf16(            \
          al.b, bh[ct], acc[RT][ct], 0, 0, 0);                          \
    }                                                                   \
  } while (0)

__global__ __launch_bounds__(256) void mlp_kernel(
    const float* __restrict__ x,
    const unsigned short* __restrict__ whT, const unsigned short* __restrict__ wlT,
    const float* __restrict__ b1, const float* __restrict__ W2,
    const float* __restrict__ b2, float* __restrict__ yv,
    float* __restrict__ zv, int N) {
  __shared__ float xs[2 * 4096];       // 2 x 16KB kc-tiles of x
  __shared__ float redy[128][2];
  __shared__ float redz[128][2];

  const int t = threadIdx.x;
  const int lane = t & 63;
  const int w = t >> 6;
  const int wr = w >> 1, wc = w & 1;           // wave grid 2x2
  const int ln15 = lane & 15, lq = lane >> 4;  // quad

  const int row0 = blockIdx.x * 128;

  f32x4 acc[4][4];  // [rt][ct]
#pragma unroll
  for (int i = 0; i < 4; ++i)
#pragma unroll
    for (int j = 0; j < 4; ++j) acc[i][j] = (f32x4){0.f, 0.f, 0.f, 0.f};

  // ---- staging source pointers (per thread, kc-invariant) ----
  // round r stages LDS rows [r*32, r*32+32); thread covers row r*32+(t>>3),
  // physical 16B slot (t&7).  Physical slot p holds LOGICAL col (p ^ swz),
  // so the global source col is pre-swizzled (rule 21: swizzle both sides).
  const float* srow[4];
  {
    const int rsub = t >> 3;                   // row within 32-row group
    const int swzs = (rsub & 7) << 4;          // row&7 == (t>>3)&7 for all r
    const int scolb = ((t & 7) * 16) ^ swzs;   // pre-swizzled source byte col
#pragma unroll
    for (int r = 0; r < 4; ++r) {
      int grow = row0 + r * 32 + rsub;
      grow = grow < N ? grow : N - 1;          // clamp: rows >=N computed, never stored
      srow[r] = x + (size_t)grow * F + (scolb >> 2);
    }
  }

  // ---- LDS read offsets (per thread, kc-invariant): logical col c of row
  // is at physical byte  row*128 + (c ^ ((row&7)<<4)) ----
  const int row_l = wr * 64 + ln15;            // + rt*16
  const int swzr = (ln15 & 7) << 4;            // row_l&7 == ln15&7
  const int p0base = row_l * 128 + ((lq * 32) ^ swzr);   // + rt*2048

  const int cbase = wc * 64 + ln15;            // + ct*16
  const unsigned short* wb = whT + cbase * 32 + lq * 8;
  const unsigned short* lb = wlT + cbase * 32 + lq * 8;

  STAGE(0, 0);                                 // prologue; waited in-loop

#pragma unroll
  for (int kc = 0; kc < 8; ++kc) {
    // B-loads first (oldest), then stage kc+1 (newest 4 outstanding)
    bf16x8 bh[4], bl[4];
#pragma unroll
    for (int ct = 0; ct < 4; ++ct) {
      bh[ct] = *(const bf16x8*)(wb + kc * 4096 + ct * 512);
      bl[ct] = *(const bf16x8*)(lb + kc * 4096 + ct * 512);
    }
    if (kc < 7) STAGE((kc + 1) & 1, kc + 1);   // async prefetch next tile

    // counted wait: STAGE(kc) (+ B, compiler also re-waits for VGPR deps)
    // complete; STAGE(kc+1)'s 4 loads stay in flight across the barrier
    // and the whole compute phase.
    asm volatile("s_waitcnt vmcnt(4)" ::: "memory");
    asm volatile("s_barrier" ::: "memory");    // buf[kc&1] visible to all

    const char* bufp = (const char*)xs + (kc & 1) * 16384;
#pragma unroll
    for (int rt = 0; rt < 4; ++rt) {
      // logical low half at p0, logical high half at p0^16 (swizzle XOR)
      const int p0 = p0base + rt * 2048;
      float4 lo = *(const float4*)(bufp + p0);
      float4 hi = *(const float4*)(bufp + (p0 ^ 16));
      SPLIT_MFMA(lo, hi, rt);
    }
    // reuse-protect: no wave may STAGE(kc+2) into buf[kc&1] until all
    // waves' reads of it are done.  Raw barrier, NO vmcnt drain.
    asm volatile("s_barrier" ::: "memory");
  }

  // ---- epilogue: h = tanh(acc + b1), contract with W2 ----
  // acc[rt][ct][rg]: row = wr*64+rt*16+lq*4+rg, col = wc*64+ct*16+ln15
  float yp[4][4], zp[4][4];
#pragma unroll
  for (int i = 0; i < 4; ++i)
#pragma unroll
    for (int j = 0; j < 4; ++j) { yp[i][j] = 0.f; zp[i][j] = 0.f; }
#pragma unroll
  for (int ct = 0; ct < 4; ++ct) {
    int c = cbase + ct * 16;
    float b1c = b1[c], wyc = W2[2 * c], wzc = W2[2 * c + 1];
#pragma unroll
    for (int rt = 0; rt < 4; ++rt)
#pragma unroll
      for (int rg = 0; rg < 4; ++rg) {
        float a = acc[rt][ct][rg] + b1c;
        float e = __expf(2.f * a);
        float h = 1.f - __fdividef(2.f, e + 1.f);   // tanh(a)
        yp[rt][rg] = fmaf(h, wyc, yp[rt][rg]);
        zp[rt][rg] = fmaf(h, wzc, zp[rt][rg]);
      }
  }
#pragma unroll
  for (int rt = 0; rt < 4; ++rt)
#pragma unroll
    for (int rg = 0; rg < 4; ++rg) {
      float vy = yp[rt][rg], vz = zp[rt][rg];
#pragma unroll
      for (int m = 8; m; m >>= 1) {
        vy += __shfl_xor(vy, m);
        vz += __shfl_xor(vz, m);
      }
      if (ln15 == 0) {
        int row = wr * 64 + rt * 16 + lq * 4 + rg;
        redy[row][wc] = vy;
        redz[row][wc] = vz;
      }
    }
  __syncthreads();
  if (t < 128) {
    int g = row0 + t;
    if (g < N) {
      yv[g] = redy[t][0] + redy[t][1] + b2[0];
      zv[g] = redz[t][0] + redz[t][1] + b2[1];
    }
  }
}
#undef STAGE
#undef SPLIT_MFMA

// ---------------------------------------------------------------------------
// K2 (fused stats+pool), unchanged (nchunks=8, reverse-stream L3 harvest).
// ---------------------------------------------------------------------------
__device__ inline float wave_reduce_sum(float v) {
#pragma unroll
  for (int o = 32; o; o >>= 1) v += __shfl_down(v, o);
  return v;
}
__device__ inline float wave_reduce_max(float v) {
#pragma unroll
  for (int o = 32; o; o >>= 1) v = fmaxf(v, __shfl_down(v, o));
  return v;
}

__global__ __launch_bounds__(256) void pool_kernel(
    const float* __restrict__ x,
    const float* __restrict__ yv, const float* __restrict__ zv,
    const int* __restrict__ offsets, const int* __restrict__ lengths,
    float* __restrict__ attn, float* __restrict__ out,
    int nchunks, int S) {
  __shared__ float ybuf[MAXL];         // 12 KB
  __shared__ float4 sbuf[4][64];       // 4 KB
  __shared__ float redA[4], redB[4], redC[4];

  const int s = S - 1 - blockIdx.y;
  const int c = nchunks - 1 - blockIdx.x;
  const int off = offsets[s], L = lengths[s];
  const int t = threadIdx.x;
  const int lane = t & 63, wid = t >> 6;   // 4 waves

  // ---- phase 1: stage y, running max ----
  float lmax = -1e30f;
  for (int i = t; i < L; i += 256) {
    float yy = yv[off + i];
    ybuf[i] = yy;
    lmax = fmaxf(lmax, yy);
  }
  lmax = wave_reduce_max(lmax);
  if (lane == 0) redA[wid] = lmax;
  __syncthreads();
  const float ymax = fmaxf(fmaxf(redA[0], redA[1]), fmaxf(redA[2], redA[3]));
  const float invL = 1.f / (float)L;
  __syncthreads();   // protect redA before reuse

  // ---- phase 2: weighted sums ----
  float sw = 0.f, smx = 0.f, sz = 0.f;
  for (int i = t; i < L; i += 256) {
    float wgt = __expf(ybuf[i] - ymax);
    float xp = (float)(i + 1) * invL;
    sw += wgt;
    smx = fmaf(xp, wgt, smx);
    sz += zv[off + i];
  }
  sw = wave_reduce_sum(sw);
  smx = wave_reduce_sum(smx);
  sz = wave_reduce_sum(sz);
  if (lane == 0) { redA[wid] = sw; redB[wid] = smx; redC[wid] = sz; }
  __syncthreads();
  const float wsum = (redA[0] + redA[1]) + (redA[2] + redA[3]);
  const float mxs  = (redB[0] + redB[1]) + (redB[2] + redB[3]);
  const float zsum = (redC[0] + redC[1]) + (redC[2] + redC[3]);
  const float mu = mxs / wsum;
  const float tz = zsum * invL;
  const float sd = fmaxf(tz, 0.f) + log1pf(__expf(-fabsf(tz)));  // softplus
  const float invsd = 1.f / sd;
  const float Cg = 0.3989422804014327f;  // 1/sqrt(2*pi)
  __syncthreads();   // protect redA before reuse

  // ---- phase 3: psum over FULL segment (pure function of i, L, mu, sd) ----
  float ps = 0.f;
  for (int i = t; i < L; i += 256) {
    float xp = (float)(i + 1) * invL;
    float u = (xp - mu) * invsd;
    ps += __expf(-0.5f * u * u);
  }
  ps = wave_reduce_sum(ps);
  if (lane == 0) redA[wid] = ps;
  __syncthreads();
  const float psum = ((redA[0] + redA[1]) + (redA[2] + redA[3])) * (Cg * invsd);
  const float scale = (Cg * invsd) / (psum + 0.001f);   // attn_i = exp(-u^2/2)*scale

  // ---- phase 4: write attn for own chunk (coalesced) ----
  const int i0 = (int)((long long)L * c / nchunks);
  const int i1 = (int)((long long)L * (c + 1) / nchunks);
  for (int i = i0 + t; i < i1; i += 256) {
    float xp = (float)(i + 1) * invL;
    float u = (xp - mu) * invsd;
    attn[off + i] = __expf(-0.5f * u * u) * scale;
  }

  // ---- phase 5: pool own chunk of x, descending rows (L3 harvest) ----
  float4 a0 = make_float4(0.f, 0.f, 0.f, 0.f);
  float4 a1 = make_float4(0.f, 0.f, 0.f, 0.f);
  int i = i1 - 1 - wid;
  for (; i - 4 >= i0; i -= 8) {
    float xpa = (float)(i + 1) * invL;
    float ua = (xpa - mu) * invsd;
    float w0 = __expf(-0.5f * ua * ua) * scale;
    float xpb = (float)(i - 3) * invL;
    float ub = (xpb - mu) * invsd;
    float w1 = __expf(-0.5f * ub * ub) * scale;
    float4 v0 = *(const float4*)&x[(size_t)(off + i) * F + lane * 4];
    float4 v1 = *(const float4*)&x[(size_t)(off + i - 4) * F + lane * 4];
    a0.x = fmaf(w0, v0.x, a0.x); a0.y = fmaf(w0, v0.y, a0.y);
    a0.z = fmaf(w0, v0.z, a0.z); a0.w = fmaf(w0, v0.w, a0.w);
    a1.x = fmaf(w1, v1.x, a1.x); a1.y = fmaf(w1, v1.y, a1.y);
    a1.z = fmaf(w1, v1.z, a1.z); a1.w = fmaf(w1, v1.w, a1.w);
  }
  if (i >= i0) {
    float xpa = (float)(i + 1) * invL;
    float ua = (xpa - mu) * invsd;
    float w0 = __expf(-0.5f * ua * ua) * scale;
    float4 v0 = *(const float4*)&x[(size_t)(off + i) * F + lane * 4];
    a0.x = fmaf(w0, v0.x, a0.x); a0.y = fmaf(w0, v0.y, a0.y);
    a0.z = fmaf(w0, v0.z, a0.z); a0.w = fmaf(w0, v0.w, a0.w);
  }
  a0.x += a1.x; a0.y += a1.y; a0.z += a1.z; a0.w += a1.w;
  sbuf[wid][lane] = a0;
  __syncthreads();
  if (wid == 0) {
    float4 r0 = sbuf[0][lane], r1 = sbuf[1][lane];
    float4 r2 = sbuf[2][lane], r3 = sbuf[3][lane];
    float rx = (r0.x + r1.x) + (r2.x + r3.x);
    float ry = (r0.y + r1.y) + (r2.y + r3.y);
    float rz = (r0.z + r1.z) + (r2.z + r3.z);
    float rw = (r0.w + r1.w) + (r2.w + r3.w);
    float* o = &out[s * F + lane * 4];
    atomicAdd(o + 0, rx);
    atomicAdd(o + 1, ry);
    atomicAdd(o + 2, rz);
    atomicAdd(o + 3, rw);
  }
}

// ---------------------------------------------------------------------------
extern "C" void kernel_launch(void* const* d_in, const int* in_sizes, int n_in,
                              void* d_out, int out_size, void* d_ws, size_t ws_size,
                              hipStream_t stream) {
  const float* x      = (const float*)d_in[0];
  const int* lengths  = (const int*)d_in[1];
  const float* W1     = (const float*)d_in[2];
  const float* b1     = (const float*)d_in[3];
  const float* W2     = (const float*)d_in[4];
  const float* b2     = (const float*)d_in[5];
  const int S = in_sizes[1];
  const int N = in_sizes[0] / F;

  float* out  = (float*)d_out;             // S*F
  float* attn = out + (size_t)S * F;       // N

  int*   offsets = (int*)d_ws;                       // 512 ints (2 KB)
  float* yv = (float*)d_ws + 512;                    // N floats
  float* zv = yv + N;                                // N floats
  unsigned short* whT = (unsigned short*)(zv + N);   // 32768 shorts (64 KB)
  unsigned short* wlT = whT + F * Hh;                // 32768 shorts (64 KB)

  init_kernel<<<64, 256, 0, stream>>>(lengths, offsets, out, W1, whT, wlT, S, S * F);
  mlp_kernel<<<(N + 127) / 128, 256, 0, stream>>>(x, whT, wlT, b1, W2, b2, yv, zv, N);
  pool_kernel<<<dim3(8, S), 256, 0, stream>>>(x, yv, zv, offsets, lengths, attn, out, 8, S);
}